// Round 7
// baseline (1811.897 us; speedup 1.0000x reference)
//
#include <hip/hip_runtime.h>
#include <hip/hip_fp16.h>

#define N_NODES 100000
#define N_EDGES 1250000
#define HID 64
#define N_GRAPHS 512
#define OUT_CH 16

#define NHS 391         // half-supers of 256 dst rows (100000/256 -> 0..390)
#define SB2_CAP 4096    // mean 3197, sigma ~56 -> +16 sigma
#define E_BLK 2048
#define NPB ((N_EDGES + E_BLK - 1) / E_BLK)  // 611
#define TILE2 ((N_NODES + 127) / 128)  // 782 blocks (2 row-tiles each)
#define NWP 6           // prepped weight matrices (W1a..W3b)
#define TSTRIDE 68      // LDS T row stride (floats)
#define SMEM_UNION 25600 // sort: 16384 srt + 4096 hist + 4096 curs + 1024 tsum

typedef _Float16 h16;
typedef _Float16 half2_t __attribute__((ext_vector_type(2)));
typedef _Float16 f16x8 __attribute__((ext_vector_type(8)));
typedef float f32x4 __attribute__((ext_vector_type(4)));

__device__ __forceinline__ unsigned pack2(float x, float y) {
    half2_t o;
    o[0] = (h16)x;
    o[1] = (h16)y;
    return __builtin_bit_cast(unsigned, o);
}

// ===========================================================================
// r22 k_part: partition edges by dst>>8 into 391 half-super buckets (512-bin
// LDS hist, 2 bins/thread) || wprep (6 blks). Record = (dst&255)<<17 | src.
// ===========================================================================
__global__ __launch_bounds__(256) void k_part(const int* __restrict__ src,
                                              const int* __restrict__ dst,
                                              int* __restrict__ cnt,
                                              int* __restrict__ buckets,
                                              const float* __restrict__ W1a,
                                              const float* __restrict__ W1b,
                                              const float* __restrict__ W2a,
                                              const float* __restrict__ W2b,
                                              const float* __restrict__ W3a,
                                              const float* __restrict__ W3b,
                                              h16* __restrict__ WF) {
    __shared__ int hist[512];
    __shared__ int gbase[512];
    __shared__ int tsum[256];
    __shared__ __align__(16) int stage[E_BLK];

    int b = blockIdx.x;
    int t = threadIdx.x;

    if (b < NPB) {
        int e0 = b * E_BLK;
        int eN = N_EDGES - e0;
        if (eN > E_BLK) eN = E_BLK;

        hist[t] = 0;
        hist[t + 256] = 0;
        __syncthreads();
        for (int i = t; i < eN; i += 256) atomicAdd(&hist[dst[e0 + i] >> 8], 1);
        __syncthreads();

        int c0 = hist[2 * t], c1 = hist[2 * t + 1];
        int tot = c0 + c1;
        tsum[t] = tot;
        __syncthreads();
        for (int off = 1; off < 256; off <<= 1) {
            int u = (t >= off) ? tsum[t - off] : 0;
            __syncthreads();
            tsum[t] += u;
            __syncthreads();
        }
        int pref = tsum[t] - tot;
        if (c0 > 0) gbase[2 * t] = atomicAdd(&cnt[2 * t], c0);
        if (c1 > 0) gbase[2 * t + 1] = atomicAdd(&cnt[2 * t + 1], c1);
        hist[2 * t] = pref;
        hist[2 * t + 1] = pref + c0;
        __syncthreads();

        for (int i = t; i < eN; i += 256) {
            int s = src[e0 + i];
            int d = dst[e0 + i];
            int p = atomicAdd(&hist[d >> 8], 1);
            stage[p] = ((d & 255) << 17) | s;
        }
        __syncthreads();

        // writeout: thread t owns bins 2t, 2t+1 (hist[bin] now = end offset)
#pragma unroll
        for (int k = 0; k < 2; ++k) {
            int bin = 2 * t + k;
            int c = k ? c1 : c0;
            if (c > 0) {
                int lstart = hist[bin] - c;
                int gb = gbase[bin];
                int cap = SB2_CAP - gb;
                int n = c < cap ? c : (cap > 0 ? cap : 0);
                int* dp = buckets + (size_t)bin * SB2_CAP + gb;
                for (int r = 0; r < n; ++r) dp[r] = stage[lstart + r];
            }
        }
    } else {
        const float* Ws[NWP] = {W1a, W1b, W2a, W2b, W3a, W3b};
        const float* W = Ws[b - NPB];
        h16* dstW = WF + (size_t)(b - NPB) * 4096;
#pragma unroll
        for (int i = 0; i < 16; ++i) {
            int s = t + 256 * i;
            int k = s >> 6, col = s & 63;
            int kc = k >> 5, quad = (k >> 3) & 3, j = k & 7;
            int c = col >> 4, n = col & 15;
            dstW[((c * 2 + kc) * 4 + quad) * 128 + n * 8 + j] = (h16)W[s];
        }
    }
}

// ===========================================================================
// r22 k_sortlin: per-bucket counting sort by src>>7 (1024 bins, 4/thread)
// for L2-streaming gather order (391 blks) || input-linear (782 blks).
// Sort order is PERF-ONLY (sums commute) — bugs here cannot corrupt output.
// ===========================================================================
__global__ __launch_bounds__(256) void k_sortlin(const int* __restrict__ cnt,
                                                 int* __restrict__ buckets,
                                                 const float* __restrict__ W0,
                                                 const float* __restrict__ B0,
                                                 const float* __restrict__ Xin,
                                                 h16* __restrict__ Hout) {
    __shared__ __align__(16) char smem[SMEM_UNION];
    int b = blockIdx.x;
    int t = threadIdx.x;

    if (b < NHS) {
        int* srt   = (int*)smem;              // 4096 ints
        int* hist2 = (int*)(smem + 16384);    // 1024 ints
        int* curs  = (int*)(smem + 20480);    // 1024 ints
        int* tsum  = (int*)(smem + 24576);    // 256 ints
        int n = cnt[b];
        n = n < SB2_CAP ? n : SB2_CAP;
        int* gb = buckets + (size_t)b * SB2_CAP;

#pragma unroll
        for (int k = 0; k < 4; ++k) hist2[t + 256 * k] = 0;
        __syncthreads();
        for (int i = t; i < n; i += 256) atomicAdd(&hist2[(gb[i] & 0x1FFFF) >> 7], 1);
        __syncthreads();

        int c[4], tot = 0;
#pragma unroll
        for (int k = 0; k < 4; ++k) { c[k] = hist2[4 * t + k]; tot += c[k]; }
        tsum[t] = tot;
        __syncthreads();
        for (int off = 1; off < 256; off <<= 1) {
            int u = (t >= off) ? tsum[t - off] : 0;
            __syncthreads();
            tsum[t] += u;
            __syncthreads();
        }
        int run = tsum[t] - tot;
#pragma unroll
        for (int k = 0; k < 4; ++k) { curs[4 * t + k] = run; run += c[k]; }
        __syncthreads();

        for (int i = t; i < n; i += 256) {
            int rec = gb[i];
            int pos = atomicAdd(&curs[(rec & 0x1FFFF) >> 7], 1);
            srt[pos] = rec;
        }
        __syncthreads();
        for (int i = t; i < n; i += 256) gb[i] = srt[i];
    } else {
        float* sT = (float*)smem;
        int lb = b - NHS;
        int w = t >> 6, lane = t & 63;
        int n16 = lane & 15, quad = lane >> 4;
        float* T = sT + w * 16 * TSTRIDE;

        f16x8 bw[4][2];
#pragma unroll
        for (int c = 0; c < 4; ++c)
#pragma unroll
            for (int kc = 0; kc < 2; ++kc) {
                f16x8 v;
#pragma unroll
                for (int j = 0; j < 8; ++j)
                    v[j] = (h16)W0[(kc * 32 + quad * 8 + j) * 64 + c * 16 + n16];
                bw[c][kc] = v;
            }
        float bv[4];
#pragma unroll
        for (int c = 0; c < 4; ++c) bv[c] = B0[c * 16 + n16];

#pragma unroll
        for (int tt = 0; tt < 2; ++tt) {
            int rbase = lb * 128 + tt * 64 + w * 16;
            int arow = rbase + n16;
            int crow = arow < N_NODES ? arow : N_NODES - 1;
            f16x8 a[2];
#pragma unroll
            for (int kc = 0; kc < 2; ++kc) {
                const float4* xp = (const float4*)(Xin + (size_t)crow * HID + kc * 32 + quad * 8);
                float4 p = xp[0], q = xp[1];
                f16x8 v;
                v[0] = (h16)p.x; v[1] = (h16)p.y; v[2] = (h16)p.z; v[3] = (h16)p.w;
                v[4] = (h16)q.x; v[5] = (h16)q.y; v[6] = (h16)q.z; v[7] = (h16)q.w;
                a[kc] = v;
            }

            f32x4 acc[4];
#pragma unroll
            for (int c = 0; c < 4; ++c) {
                acc[c] = (f32x4){bv[c], bv[c], bv[c], bv[c]};
#pragma unroll
                for (int kc = 0; kc < 2; ++kc)
                    acc[c] = __builtin_amdgcn_mfma_f32_16x16x32_f16(a[kc], bw[c][kc], acc[c], 0, 0, 0);
            }

#pragma unroll
            for (int c = 0; c < 4; ++c)
#pragma unroll
                for (int r = 0; r < 4; ++r)
                    T[(quad * 4 + r) * TSTRIDE + c * 16 + n16] = fmaxf(acc[c][r], 0.f);
            {
                int rl = lane >> 2, seg = lane & 3;
                int row = rbase + rl;
                if (row < N_NODES) {
                    const float* tr = &T[rl * TSTRIDE + seg * 16];
                    f16x8 o0, o1;
#pragma unroll
                    for (int i = 0; i < 8; ++i) {
                        o0[i] = (h16)tr[i];
                        o1[i] = (h16)tr[8 + i];
                    }
                    f16x8* dp = (f16x8*)(Hout + (size_t)row * HID + seg * 16);
                    dp[0] = o0;
                    dp[1] = o1;
                }
            }
            __syncthreads();
        }
    }
}

// ===========================================================================
// r22 k_aggregate: LDS fp32 accumulator per 256-dst half-super. Block owns
// rows [hs*256, +256) as acc[256][65] fp32 (65-pad -> ~2-way banks). Edges
// pre-sorted by src>>7 -> the gather walks H ascending; ~49 blocks/XCD sweep
// in near-lockstep -> L2-resident window. 8-lane groups, 2-deep pipelined
// loads, 8 LDS atomicAdds/lane (distinct rows -> no same-address storms).
// ===========================================================================
__global__ __launch_bounds__(256) void k_aggregate(const int* __restrict__ cnt,
                                                   const int* __restrict__ buckets,
                                                   const h16* __restrict__ H,
                                                   h16* __restrict__ Z) {
    __shared__ float acc[256 * 65];   // 66560 B
    const uint4* H8 = (const uint4*)H;
    uint4* Z8 = (uint4*)Z;
    int hs = blockIdx.x;
    int t = threadIdx.x;
    int dstBase = hs << 8;
    int rsub = t & 7;                 // 16B chunk within a row

    // ---- self-term init: coalesced H read -> fp32 LDS (conflict-light) ----
#pragma unroll
    for (int p = 0; p < 8; ++p) {
        int r = p * 32 + (t >> 3);
        int rowg = dstBase + r;
        uint4 u = H8[(size_t)(rowg < N_NODES ? rowg : N_NODES - 1) * 8 + rsub];
        float* ap = &acc[r * 65 + rsub * 8];
        half2_t h0 = __builtin_bit_cast(half2_t, u.x);
        half2_t h1 = __builtin_bit_cast(half2_t, u.y);
        half2_t h2 = __builtin_bit_cast(half2_t, u.z);
        half2_t h3 = __builtin_bit_cast(half2_t, u.w);
        bool v = rowg < N_NODES;
        ap[0] = v ? (float)h0[0] : 0.f;
        ap[1] = v ? (float)h0[1] : 0.f;
        ap[2] = v ? (float)h1[0] : 0.f;
        ap[3] = v ? (float)h1[1] : 0.f;
        ap[4] = v ? (float)h2[0] : 0.f;
        ap[5] = v ? (float)h2[1] : 0.f;
        ap[6] = v ? (float)h3[0] : 0.f;
        ap[7] = v ? (float)h3[1] : 0.f;
    }
    __syncthreads();

    // ---- edge accumulation: 32 groups x 8 lanes, 2-deep pipeline ----
    int n = cnt[hs];
    n = n < SB2_CAP ? n : SB2_CAP;
    const int* gb = buckets + (size_t)hs * SB2_CAP;
    int g = t >> 3;
    int e = g;
    int rec = (e < n) ? gb[e] : -1;
    uint4 u = {};
    if (rec >= 0) u = H8[(size_t)(rec & 0x1FFFF) * 8 + rsub];
    while (rec >= 0) {
        int en = e + 32;
        int recn = (en < n) ? gb[en] : -1;
        uint4 un = u;
        if (recn >= 0) un = H8[(size_t)(recn & 0x1FFFF) * 8 + rsub];
        float* ap = &acc[((rec >> 17) & 255) * 65 + rsub * 8];
        half2_t h0 = __builtin_bit_cast(half2_t, u.x);
        half2_t h1 = __builtin_bit_cast(half2_t, u.y);
        half2_t h2 = __builtin_bit_cast(half2_t, u.z);
        half2_t h3 = __builtin_bit_cast(half2_t, u.w);
        atomicAdd(ap + 0, (float)h0[0]);
        atomicAdd(ap + 1, (float)h0[1]);
        atomicAdd(ap + 2, (float)h1[0]);
        atomicAdd(ap + 3, (float)h1[1]);
        atomicAdd(ap + 4, (float)h2[0]);
        atomicAdd(ap + 5, (float)h2[1]);
        atomicAdd(ap + 6, (float)h3[0]);
        atomicAdd(ap + 7, (float)h3[1]);
        e = en;
        rec = recn;
        u = un;
    }
    __syncthreads();

    // ---- writeout: fp32 -> fp16, coalesced ----
#pragma unroll
    for (int p = 0; p < 8; ++p) {
        int r = p * 32 + (t >> 3);
        int rowg = dstBase + r;
        if (rowg < N_NODES) {
            const float* ap = &acc[r * 65 + rsub * 8];
            uint4 o;
            o.x = pack2(ap[0], ap[1]);
            o.y = pack2(ap[2], ap[3]);
            o.z = pack2(ap[4], ap[5]);
            o.w = pack2(ap[6], ap[7]);
            Z8[(size_t)rowg * 8 + rsub] = o;
        }
    }
}

// ===========================================================================
// MFMA MLP r16 (proven): 2 row-tiles (128 rows) per block, B-frags reused.
// ===========================================================================
__global__ __launch_bounds__(256) void k_mlp(const h16* __restrict__ WaF,
                                             const float* __restrict__ Ba,
                                             const h16* __restrict__ WbF,
                                             const float* __restrict__ Bb,
                                             const h16* __restrict__ Zin,
                                             h16* __restrict__ Hout) {
    __shared__ __align__(16) float sT[4 * 16 * TSTRIDE];
    int t = threadIdx.x;
    int w = t >> 6, lane = t & 63;
    int n16 = lane & 15, quad = lane >> 4;
    float* T = sT + w * 16 * TSTRIDE;

    f16x8 bwa[4][2], bwb[4][2];
#pragma unroll
    for (int c = 0; c < 4; ++c)
#pragma unroll
        for (int kc = 0; kc < 2; ++kc) {
            int f = ((c * 2 + kc) * 4 + quad) * 128 + n16 * 8;
            bwa[c][kc] = *(const f16x8*)(WaF + f);
            bwb[c][kc] = *(const f16x8*)(WbF + f);
        }
    float bva[4], bvb[4];
#pragma unroll
    for (int c = 0; c < 4; ++c) {
        bva[c] = Ba[c * 16 + n16];
        bvb[c] = Bb[c * 16 + n16];
    }

#pragma unroll
    for (int tt = 0; tt < 2; ++tt) {
        int rbase = blockIdx.x * 128 + tt * 64 + w * 16;
        int arow = rbase + n16;
        int crow = arow < N_NODES ? arow : N_NODES - 1;
        const f16x8* zp = (const f16x8*)(Zin + (size_t)crow * HID + quad * 8);
        f16x8 a0 = zp[0];
        f16x8 a1 = zp[4];

        f32x4 acc[4];
#pragma unroll
        for (int c = 0; c < 4; ++c) {
            acc[c] = (f32x4){bva[c], bva[c], bva[c], bva[c]};
            acc[c] = __builtin_amdgcn_mfma_f32_16x16x32_f16(a0, bwa[c][0], acc[c], 0, 0, 0);
            acc[c] = __builtin_amdgcn_mfma_f32_16x16x32_f16(a1, bwa[c][1], acc[c], 0, 0, 0);
        }

#pragma unroll
        for (int c = 0; c < 4; ++c)
#pragma unroll
            for (int r = 0; r < 4; ++r)
                T[(quad * 4 + r) * TSTRIDE + c * 16 + n16] = fmaxf(acc[c][r], 0.f);

        f16x8 ta[2];
#pragma unroll
        for (int kc = 0; kc < 2; ++kc) {
            float4 p = *(const float4*)&T[n16 * TSTRIDE + kc * 32 + quad * 8];
            float4 q = *(const float4*)&T[n16 * TSTRIDE + kc * 32 + quad * 8 + 4];
            f16x8 v;
            v[0] = (h16)p.x; v[1] = (h16)p.y; v[2] = (h16)p.z; v[3] = (h16)p.w;
            v[4] = (h16)q.x; v[5] = (h16)q.y; v[6] = (h16)q.z; v[7] = (h16)q.w;
            ta[kc] = v;
        }

#pragma unroll
        for (int c = 0; c < 4; ++c) {
            acc[c] = (f32x4){bvb[c], bvb[c], bvb[c], bvb[c]};
            acc[c] = __builtin_amdgcn_mfma_f32_16x16x32_f16(ta[0], bwb[c][0], acc[c], 0, 0, 0);
            acc[c] = __builtin_amdgcn_mfma_f32_16x16x32_f16(ta[1], bwb[c][1], acc[c], 0, 0, 0);
        }

#pragma unroll
        for (int c = 0; c < 4; ++c)
#pragma unroll
            for (int r = 0; r < 4; ++r)
                T[(quad * 4 + r) * TSTRIDE + c * 16 + n16] = fmaxf(acc[c][r], 0.f);
        {
            int rl = lane >> 2, seg = lane & 3;
            int row = rbase + rl;
            if (row < N_NODES) {
                const float* tr = &T[rl * TSTRIDE + seg * 16];
                f16x8 o0, o1;
#pragma unroll
                for (int i = 0; i < 8; ++i) {
                    o0[i] = (h16)tr[i];
                    o1[i] = (h16)tr[8 + i];
                }
                f16x8* dp = (f16x8*)(Hout + (size_t)row * HID + seg * 16);
                dp[0] = o0;
                dp[1] = o1;
            }
        }
    }
}

// ===========================================================================
// Fused mean-pool + readout (r16/r20 proven). Restored after r21 regression.
// ===========================================================================
__global__ __launch_bounds__(256) void k_poolfinal(const h16* __restrict__ H,
                                                   const int* __restrict__ batch,
                                                   const float* __restrict__ Wl,
                                                   const float* __restrict__ bl,
                                                   float* __restrict__ out) {
    __shared__ float sp[4 * HID];
    int g = blockIdx.x;
    int t = threadIdx.x;
    int lane = t & 63, w = t >> 6;
    int lo = 0, hi = N_NODES;
    while (lo < hi) { int m = (lo + hi) >> 1; if (batch[m] < g) lo = m + 1; else hi = m; }
    int start = lo;
    hi = N_NODES;
    while (lo < hi) { int m = (lo + hi) >> 1; if (batch[m] < g + 1) lo = m + 1; else hi = m; }
    int end = lo;
    float s0 = 0.f, s1 = 0.f, s2 = 0.f, s3 = 0.f;
    int r = start + w;
    for (; r + 12 < end; r += 16) {
        float v0 = (float)H[(size_t)r * HID + lane];
        float v1 = (float)H[(size_t)(r + 4) * HID + lane];
        float v2 = (float)H[(size_t)(r + 8) * HID + lane];
        float v3 = (float)H[(size_t)(r + 12) * HID + lane];
        s0 += v0; s1 += v1; s2 += v2; s3 += v3;
    }
    for (; r < end; r += 4) s0 += (float)H[(size_t)r * HID + lane];
    sp[w * HID + lane] = s0 + s1 + s2 + s3;
    __syncthreads();
    if (t < HID) {
        float tot = sp[t] + sp[HID + t] + sp[2 * HID + t] + sp[3 * HID + t];
        float c = (end > start) ? (float)(end - start) : 1.0f;
        sp[t] = tot / c;
    }
    __syncthreads();
    if (t < OUT_CH) {
        float acc = bl[t];
#pragma unroll
        for (int k = 0; k < HID; ++k) acc += sp[k] * Wl[k * OUT_CH + t];
        out[g * OUT_CH + t] = acc;
    }
}

extern "C" void kernel_launch(void* const* d_in, const int* in_sizes, int n_in,
                              void* d_out, int out_size, void* d_ws, size_t ws_size,
                              hipStream_t stream) {
    const float* x     = (const float*)d_in[0];
    const int*   edge  = (const int*)d_in[1];   // [2][N_EDGES] int32
    const int*   batch = (const int*)d_in[2];   // [N_NODES] int32 (sorted)
    const float* W0  = (const float*)d_in[3];
    const float* b0  = (const float*)d_in[4];
    const float* W1a = (const float*)d_in[5];
    const float* b1a = (const float*)d_in[6];
    const float* W1b = (const float*)d_in[7];
    const float* b1b = (const float*)d_in[8];
    const float* W2a = (const float*)d_in[9];
    const float* b2a = (const float*)d_in[10];
    const float* W2b = (const float*)d_in[11];
    const float* b2b = (const float*)d_in[12];
    const float* W3a = (const float*)d_in[13];
    const float* b3a = (const float*)d_in[14];
    const float* W3b = (const float*)d_in[15];
    const float* b3b = (const float*)d_in[16];
    const float* Wl  = (const float*)d_in[17];
    const float* bl  = (const float*)d_in[18];
    float* out = (float*)d_out;

    const int* src = edge;
    const int* dst = edge + N_EDGES;

    // Workspace: HA(fp16) | Z(fp16) | cnt | buckets | WF(fp16 x6)
    h16* HA = (h16*)d_ws;
    h16* Z  = HA + (size_t)N_NODES * HID;
    int* cnt     = (int*)(Z + (size_t)N_NODES * HID);
    int* buckets = cnt + NHS;
    h16* WF      = (h16*)(buckets + (size_t)NHS * SB2_CAP);
    h16* W1aF = WF;               // order: W1a, W1b, W2a, W2b, W3a, W3b
    h16* W1bF = WF + 4096 * 1;
    h16* W2aF = WF + 4096 * 2;
    h16* W2bF = WF + 4096 * 3;
    h16* W3aF = WF + 4096 * 4;
    h16* W3bF = WF + 4096 * 5;

    hipMemsetAsync(cnt, 0, NHS * sizeof(int), stream);
    k_part<<<NPB + NWP, 256, 0, stream>>>(src, dst, cnt, buckets,
        W1a, W1b, W2a, W2b, W3a, W3b, WF);
    k_sortlin<<<NHS + TILE2, 256, 0, stream>>>(cnt, buckets, W0, b0, x, HA);

    k_aggregate<<<NHS, 256, 0, stream>>>(cnt, buckets, HA, Z);
    k_mlp<<<TILE2, 256, 0, stream>>>(W1aF, b1a, W1bF, b1b, Z, HA);

    k_aggregate<<<NHS, 256, 0, stream>>>(cnt, buckets, HA, Z);
    k_mlp<<<TILE2, 256, 0, stream>>>(W2aF, b2a, W2bF, b2b, Z, HA);

    k_aggregate<<<NHS, 256, 0, stream>>>(cnt, buckets, HA, Z);
    k_mlp<<<TILE2, 256, 0, stream>>>(W3aF, b3a, W3bF, b3b, Z, HA);

    k_poolfinal<<<N_GRAPHS, 256, 0, stream>>>(HA, batch, Wl, bl, out);
}

// Round 8
// 282.899 us; speedup vs baseline: 6.4047x; 6.4047x over previous
//
#include <hip/hip_runtime.h>
#include <hip/hip_fp16.h>

#define N_NODES 100000
#define N_EDGES 1250000
#define HID 64
#define N_GRAPHS 512
#define OUT_CH 16

#define NSUP 196        // super-buckets of 512 nodes
#define SB_CAP 8192     // mean 6378, sigma ~80 -> +22σ
#define E_BLK 2048
#define NPB ((N_EDGES + E_BLK - 1) / E_BLK)  // 611
#define TILE2 ((N_NODES + 127) / 128)  // 782
#define NWP 6           // prepped weight matrices (W1a..W3b)
#define TSTRIDE 68      // LDS T row stride (floats)
#define SMEM_UNION 37888 // sort: 32768 srt + 2048 hist + 2048 curs + 1024 tsum

// r23 layer pipeline split (multiple of 128 and 32)
#define SPLIT 49920
#define AGA_BLKS (SPLIT / 32)                      // 1560 (exact)
#define AGB_BLKS ((N_NODES - SPLIT + 31) / 32)     // 1565 (exact: 50080/32)
#define MLPA_BLKS (SPLIT / 128)                    // 390 (exact)
#define MLPB_BLKS ((N_NODES - SPLIT + 127) / 128)  // 392

typedef _Float16 h16;
typedef _Float16 half2_t __attribute__((ext_vector_type(2)));
typedef _Float16 f16x8 __attribute__((ext_vector_type(8)));
typedef float f32x4 __attribute__((ext_vector_type(4)));

__device__ __forceinline__ void acc8(uint4 u, float* a) {
    half2_t h0 = __builtin_bit_cast(half2_t, u.x);
    half2_t h1 = __builtin_bit_cast(half2_t, u.y);
    half2_t h2 = __builtin_bit_cast(half2_t, u.z);
    half2_t h3 = __builtin_bit_cast(half2_t, u.w);
    a[0] += (float)h0[0]; a[1] += (float)h0[1];
    a[2] += (float)h1[0]; a[3] += (float)h1[1];
    a[4] += (float)h2[0]; a[5] += (float)h2[1];
    a[6] += (float)h3[0]; a[7] += (float)h3[1];
}

__device__ __forceinline__ unsigned pack2(float x, float y) {
    half2_t o;
    o[0] = (h16)x;
    o[1] = (h16)y;
    return __builtin_bit_cast(unsigned, o);
}

// ---------------------------------------------------------------------------
// r19 aggregate body (proven, at its memory-service floor): 8 rows per wave,
// 8 lanes x 16B per row, 8-deep pipelined gathers.
// ---------------------------------------------------------------------------
__device__ __forceinline__ void agg8rows(const int* __restrict__ rowptrS,
                                         const int* __restrict__ buckets,
                                         const uint4* __restrict__ H8,
                                         uint4* __restrict__ Z8,
                                         int i0, int rhi, int part, int sub) {
    int i = i0 + part;
    bool valid = i < rhi;
    int iv = valid ? i : rhi - 1;
    int s = iv >> 9, l = iv & 511;
    int start = rowptrS[s * 513 + l];
    int end = valid ? rowptrS[s * 513 + l + 1] : start;
    float a[8] = {0.f, 0.f, 0.f, 0.f, 0.f, 0.f, 0.f, 0.f};
    acc8(H8[(size_t)iv * 8 + sub], a);
    int j = start;
    for (; j + 8 <= end; j += 8) {
        int s0 = buckets[j] & 0x1FFFF;
        int s1 = buckets[j + 1] & 0x1FFFF;
        int s2 = buckets[j + 2] & 0x1FFFF;
        int s3 = buckets[j + 3] & 0x1FFFF;
        int s4 = buckets[j + 4] & 0x1FFFF;
        int s5 = buckets[j + 5] & 0x1FFFF;
        int s6 = buckets[j + 6] & 0x1FFFF;
        int s7 = buckets[j + 7] & 0x1FFFF;
        uint4 u0 = H8[(size_t)s0 * 8 + sub];
        uint4 u1 = H8[(size_t)s1 * 8 + sub];
        uint4 u2 = H8[(size_t)s2 * 8 + sub];
        uint4 u3 = H8[(size_t)s3 * 8 + sub];
        uint4 u4 = H8[(size_t)s4 * 8 + sub];
        uint4 u5 = H8[(size_t)s5 * 8 + sub];
        uint4 u6 = H8[(size_t)s6 * 8 + sub];
        uint4 u7 = H8[(size_t)s7 * 8 + sub];
        acc8(u0, a); acc8(u1, a); acc8(u2, a); acc8(u3, a);
        acc8(u4, a); acc8(u5, a); acc8(u6, a); acc8(u7, a);
    }
    if (j + 4 <= end) {
        int s0 = buckets[j] & 0x1FFFF;
        int s1 = buckets[j + 1] & 0x1FFFF;
        int s2 = buckets[j + 2] & 0x1FFFF;
        int s3 = buckets[j + 3] & 0x1FFFF;
        uint4 u0 = H8[(size_t)s0 * 8 + sub];
        uint4 u1 = H8[(size_t)s1 * 8 + sub];
        uint4 u2 = H8[(size_t)s2 * 8 + sub];
        uint4 u3 = H8[(size_t)s3 * 8 + sub];
        acc8(u0, a); acc8(u1, a); acc8(u2, a); acc8(u3, a);
        j += 4;
    }
    if (j + 2 <= end) {
        int s0 = buckets[j] & 0x1FFFF;
        int s1 = buckets[j + 1] & 0x1FFFF;
        uint4 u0 = H8[(size_t)s0 * 8 + sub];
        uint4 u1 = H8[(size_t)s1 * 8 + sub];
        acc8(u0, a); acc8(u1, a);
        j += 2;
    }
    if (j < end) {
        int s0 = buckets[j] & 0x1FFFF;
        acc8(H8[(size_t)s0 * 8 + sub], a);
    }
    if (valid) {
        uint4 o;
        o.x = pack2(a[0], a[1]);
        o.y = pack2(a[2], a[3]);
        o.z = pack2(a[4], a[5]);
        o.w = pack2(a[6], a[7]);
        Z8[(size_t)i * 8 + sub] = o;
    }
}

// ---------------------------------------------------------------------------
// r16 MLP body (proven): one 128-row tile (2x64), B-frags reused across tiles.
// ---------------------------------------------------------------------------
__device__ __forceinline__ void mlp_tile128(const h16* __restrict__ WaF,
                                            const float* __restrict__ Ba,
                                            const h16* __restrict__ WbF,
                                            const float* __restrict__ Bb,
                                            const h16* __restrict__ Zin,
                                            h16* __restrict__ Hout,
                                            int row0, float* T, int w, int lane) {
    int n16 = lane & 15, quad = lane >> 4;

    f16x8 bwa[4][2], bwb[4][2];
#pragma unroll
    for (int c = 0; c < 4; ++c)
#pragma unroll
        for (int kc = 0; kc < 2; ++kc) {
            int f = ((c * 2 + kc) * 4 + quad) * 128 + n16 * 8;
            bwa[c][kc] = *(const f16x8*)(WaF + f);
            bwb[c][kc] = *(const f16x8*)(WbF + f);
        }
    float bva[4], bvb[4];
#pragma unroll
    for (int c = 0; c < 4; ++c) {
        bva[c] = Ba[c * 16 + n16];
        bvb[c] = Bb[c * 16 + n16];
    }

#pragma unroll
    for (int tt = 0; tt < 2; ++tt) {
        int rbase = row0 + tt * 64 + w * 16;
        int arow = rbase + n16;
        int crow = arow < N_NODES ? arow : N_NODES - 1;
        const f16x8* zp = (const f16x8*)(Zin + (size_t)crow * HID + quad * 8);
        f16x8 a0 = zp[0];
        f16x8 a1 = zp[4];

        f32x4 acc[4];
#pragma unroll
        for (int c = 0; c < 4; ++c) {
            acc[c] = (f32x4){bva[c], bva[c], bva[c], bva[c]};
            acc[c] = __builtin_amdgcn_mfma_f32_16x16x32_f16(a0, bwa[c][0], acc[c], 0, 0, 0);
            acc[c] = __builtin_amdgcn_mfma_f32_16x16x32_f16(a1, bwa[c][1], acc[c], 0, 0, 0);
        }

#pragma unroll
        for (int c = 0; c < 4; ++c)
#pragma unroll
            for (int r = 0; r < 4; ++r)
                T[(quad * 4 + r) * TSTRIDE + c * 16 + n16] = fmaxf(acc[c][r], 0.f);

        f16x8 ta[2];
#pragma unroll
        for (int kc = 0; kc < 2; ++kc) {
            float4 p = *(const float4*)&T[n16 * TSTRIDE + kc * 32 + quad * 8];
            float4 q = *(const float4*)&T[n16 * TSTRIDE + kc * 32 + quad * 8 + 4];
            f16x8 v;
            v[0] = (h16)p.x; v[1] = (h16)p.y; v[2] = (h16)p.z; v[3] = (h16)p.w;
            v[4] = (h16)q.x; v[5] = (h16)q.y; v[6] = (h16)q.z; v[7] = (h16)q.w;
            ta[kc] = v;
        }

#pragma unroll
        for (int c = 0; c < 4; ++c) {
            acc[c] = (f32x4){bvb[c], bvb[c], bvb[c], bvb[c]};
            acc[c] = __builtin_amdgcn_mfma_f32_16x16x32_f16(ta[0], bwb[c][0], acc[c], 0, 0, 0);
            acc[c] = __builtin_amdgcn_mfma_f32_16x16x32_f16(ta[1], bwb[c][1], acc[c], 0, 0, 0);
        }

#pragma unroll
        for (int c = 0; c < 4; ++c)
#pragma unroll
            for (int r = 0; r < 4; ++r)
                T[(quad * 4 + r) * TSTRIDE + c * 16 + n16] = fmaxf(acc[c][r], 0.f);
        {
            int rl = lane >> 2, seg = lane & 3;
            int row = rbase + rl;
            if (row < N_NODES) {
                const float* tr = &T[rl * TSTRIDE + seg * 16];
                f16x8 o0, o1;
#pragma unroll
                for (int i = 0; i < 8; ++i) {
                    o0[i] = (h16)tr[i];
                    o1[i] = (h16)tr[8 + i];
                }
                f16x8* dp = (f16x8*)(Hout + (size_t)row * HID + seg * 16);
                dp[0] = o0;
                dp[1] = o1;
            }
        }
    }
}

// ===========================================================================
// k_part (r20 proven): partition by dst>>9 (611 blks) || wprep (6 blks).
// ===========================================================================
__global__ __launch_bounds__(256) void k_part(const int* __restrict__ src,
                                              const int* __restrict__ dst,
                                              int* __restrict__ cnt,
                                              int* __restrict__ buckets,
                                              const float* __restrict__ W1a,
                                              const float* __restrict__ W1b,
                                              const float* __restrict__ W2a,
                                              const float* __restrict__ W2b,
                                              const float* __restrict__ W3a,
                                              const float* __restrict__ W3b,
                                              h16* __restrict__ WF) {
    __shared__ int hist[256];
    __shared__ int gbase[256];
    __shared__ int tsum[256];
    __shared__ __align__(16) int stage[E_BLK];

    int b = blockIdx.x;
    int t = threadIdx.x;

    if (b < NPB) {
        int e0 = b * E_BLK;
        int eN = N_EDGES - e0;
        if (eN > E_BLK) eN = E_BLK;

        hist[t] = 0;
        __syncthreads();
        for (int i = t; i < eN; i += 256) atomicAdd(&hist[dst[e0 + i] >> 9], 1);
        __syncthreads();

        int c = hist[t];
        tsum[t] = c;
        __syncthreads();
        for (int off = 1; off < 256; off <<= 1) {
            int u = (t >= off) ? tsum[t - off] : 0;
            __syncthreads();
            tsum[t] += u;
            __syncthreads();
        }
        int pref = tsum[t] - c;
        if (t < NSUP && c > 0) gbase[t] = atomicAdd(&cnt[t], c);
        hist[t] = pref;
        __syncthreads();

        for (int i = t; i < eN; i += 256) {
            int s = src[e0 + i];
            int d = dst[e0 + i];
            int p = atomicAdd(&hist[d >> 9], 1);
            stage[p] = ((d & 511) << 17) | s;
        }
        __syncthreads();

        if (t < NSUP && c > 0) {
            int lstart = hist[t] - c;
            int gb = gbase[t];
            int cap = SB_CAP - gb;
            int n = c < cap ? c : (cap > 0 ? cap : 0);
            int* dp = buckets + (size_t)t * SB_CAP + gb;
            int r = 0;
            while (r < n && (((size_t)(dp + r)) & 15)) { dp[r] = stage[lstart + r]; ++r; }
            for (; r + 4 <= n; r += 4) {
                int4 v;
                v.x = stage[lstart + r];
                v.y = stage[lstart + r + 1];
                v.z = stage[lstart + r + 2];
                v.w = stage[lstart + r + 3];
                *(int4*)(dp + r) = v;
            }
            for (; r < n; ++r) dp[r] = stage[lstart + r];
        }
    } else {
        const float* Ws[NWP] = {W1a, W1b, W2a, W2b, W3a, W3b};
        const float* W = Ws[b - NPB];
        h16* dstW = WF + (size_t)(b - NPB) * 4096;
#pragma unroll
        for (int i = 0; i < 16; ++i) {
            int s = t + 256 * i;
            int k = s >> 6, col = s & 63;
            int kc = k >> 5, quad = (k >> 3) & 3, j = k & 7;
            int c = col >> 4, n = col & 15;
            dstW[((c * 2 + kc) * 4 + quad) * 128 + n * 8 + j] = (h16)W[s];
        }
    }
}

// ===========================================================================
// k_sortlin (r20 proven): counting sort by 9-bit dstLocal (196 blks) ||
// input-linear (782 blks), LDS-unioned.
// ===========================================================================
__global__ __launch_bounds__(256) void k_sortlin(const int* __restrict__ cnt,
                                                 int* __restrict__ buckets,
                                                 int* __restrict__ rowptrS,
                                                 const float* __restrict__ W0,
                                                 const float* __restrict__ B0,
                                                 const float* __restrict__ Xin,
                                                 h16* __restrict__ Hout) {
    __shared__ __align__(16) char smem[SMEM_UNION];
    int b = blockIdx.x;
    int t = threadIdx.x;

    if (b < NSUP) {
        int* srt  = (int*)smem;
        int* hist = (int*)(smem + 32768);
        int* curs = (int*)(smem + 34816);
        int* tsum = (int*)(smem + 36864);
        int s = b;
        int n = cnt[s];
        n = n < SB_CAP ? n : SB_CAP;
        int* gb = buckets + (size_t)s * SB_CAP;
        int sBase = s * SB_CAP;

        hist[t] = 0;
        hist[t + 256] = 0;
        __syncthreads();
        for (int i = t; i < n; i += 256) atomicAdd(&hist[gb[i] >> 17], 1);
        __syncthreads();

        int c0 = hist[2 * t], c1 = hist[2 * t + 1];
        int tot = c0 + c1;
        tsum[t] = tot;
        __syncthreads();
        for (int off = 1; off < 256; off <<= 1) {
            int u = (t >= off) ? tsum[t - off] : 0;
            __syncthreads();
            tsum[t] += u;
            __syncthreads();
        }
        int pref = tsum[t] - tot;
        curs[2 * t] = pref;
        curs[2 * t + 1] = pref + c0;
        rowptrS[s * 513 + 2 * t] = sBase + pref;
        rowptrS[s * 513 + 2 * t + 1] = sBase + pref + c0;
        if (t == 255) rowptrS[s * 513 + 512] = sBase + n;
        __syncthreads();

        for (int i = t; i < n; i += 256) {
            int rec = gb[i];
            int pos = atomicAdd(&curs[rec >> 17], 1);
            srt[pos] = rec;
        }
        __syncthreads();
        for (int i = t; i < n; i += 256) gb[i] = srt[i];
    } else {
        float* sT = (float*)smem;
        int lb = b - NSUP;
        int w = t >> 6, lane = t & 63;
        int n16 = lane & 15, quad = lane >> 4;
        float* T = sT + w * 16 * TSTRIDE;

        f16x8 bw[4][2];
#pragma unroll
        for (int c = 0; c < 4; ++c)
#pragma unroll
            for (int kc = 0; kc < 2; ++kc) {
                f16x8 v;
#pragma unroll
                for (int j = 0; j < 8; ++j)
                    v[j] = (h16)W0[(kc * 32 + quad * 8 + j) * 64 + c * 16 + n16];
                bw[c][kc] = v;
            }
        float bv[4];
#pragma unroll
        for (int c = 0; c < 4; ++c) bv[c] = B0[c * 16 + n16];

#pragma unroll
        for (int tt = 0; tt < 2; ++tt) {
            int rbase = lb * 128 + tt * 64 + w * 16;
            int arow = rbase + n16;
            int crow = arow < N_NODES ? arow : N_NODES - 1;
            f16x8 a[2];
#pragma unroll
            for (int kc = 0; kc < 2; ++kc) {
                const float4* xp = (const float4*)(Xin + (size_t)crow * HID + kc * 32 + quad * 8);
                float4 p = xp[0], q = xp[1];
                f16x8 v;
                v[0] = (h16)p.x; v[1] = (h16)p.y; v[2] = (h16)p.z; v[3] = (h16)p.w;
                v[4] = (h16)q.x; v[5] = (h16)q.y; v[6] = (h16)q.z; v[7] = (h16)q.w;
                a[kc] = v;
            }

            f32x4 acc[4];
#pragma unroll
            for (int c = 0; c < 4; ++c) {
                acc[c] = (f32x4){bv[c], bv[c], bv[c], bv[c]};
#pragma unroll
                for (int kc = 0; kc < 2; ++kc)
                    acc[c] = __builtin_amdgcn_mfma_f32_16x16x32_f16(a[kc], bw[c][kc], acc[c], 0, 0, 0);
            }

#pragma unroll
            for (int c = 0; c < 4; ++c)
#pragma unroll
                for (int r = 0; r < 4; ++r)
                    T[(quad * 4 + r) * TSTRIDE + c * 16 + n16] = fmaxf(acc[c][r], 0.f);
            {
                int rl = lane >> 2, seg = lane & 3;
                int row = rbase + rl;
                if (row < N_NODES) {
                    const float* tr = &T[rl * TSTRIDE + seg * 16];
                    f16x8 o0, o1;
#pragma unroll
                    for (int i = 0; i < 8; ++i) {
                        o0[i] = (h16)tr[i];
                        o1[i] = (h16)tr[8 + i];
                    }
                    f16x8* dp = (f16x8*)(Hout + (size_t)row * HID + seg * 16);
                    dp[0] = o0;
                    dp[1] = o1;
                }
            }
            __syncthreads();
        }
    }
}

// ===========================================================================
// r23 aggA: rows [rlo, rhi), exact grid, r19 body.
// ===========================================================================
__global__ __launch_bounds__(256) void k_aggregate(const int* __restrict__ rowptrS,
                                                   const int* __restrict__ buckets,
                                                   const h16* __restrict__ H,
                                                   h16* __restrict__ Z,
                                                   int rlo, int rhi) {
    const uint4* H8 = (const uint4*)H;
    uint4* Z8 = (uint4*)Z;
    int lane = threadIdx.x & 63;
    int part = lane >> 3, sub = lane & 7;
    int gwave = (blockIdx.x * 256 + threadIdx.x) >> 6;
    int nw = (gridDim.x * 256) >> 6;
    for (int i0 = rlo + gwave * 8; i0 < rhi; i0 += nw * 8)
        agg8rows(rowptrS, buckets, H8, Z8, i0, rhi, part, sub);
}

// ===========================================================================
// r23 fat: aggB rows [SPLIT, N) (1565 blks) || mlpA rows [0, SPLIT) (390 blks).
// Race-free: aggB writes Z-upper & reads Hin; mlpA reads Z-lower (written by
// the previous aggA dispatch) & writes Hout-lower; Hin != Hout.
// mlp MFMA/LDS work rides the CUs' idle pipes while agg waves stall on memory.
// ===========================================================================
__global__ __launch_bounds__(256) void k_aggmlp2(const int* __restrict__ rowptrS,
                                                 const int* __restrict__ buckets,
                                                 const h16* __restrict__ Hin,
                                                 h16* __restrict__ Z,
                                                 const h16* __restrict__ WaF,
                                                 const float* __restrict__ Ba,
                                                 const h16* __restrict__ WbF,
                                                 const float* __restrict__ Bb,
                                                 h16* __restrict__ Hout) {
    __shared__ __align__(16) float sT[4 * 16 * TSTRIDE];
    int b = blockIdx.x;
    int t = threadIdx.x;
    if (b < AGB_BLKS) {
        const uint4* H8 = (const uint4*)Hin;
        uint4* Z8 = (uint4*)Z;
        int lane = t & 63;
        int part = lane >> 3, sub = lane & 7;
        int gwave = (b * 256 + t) >> 6;
        int nw = (AGB_BLKS * 256) >> 6;
        for (int i0 = SPLIT + gwave * 8; i0 < N_NODES; i0 += nw * 8)
            agg8rows(rowptrS, buckets, H8, Z8, i0, N_NODES, part, sub);
    } else {
        int lb = b - AGB_BLKS;
        int w = t >> 6, lane = t & 63;
        mlp_tile128(WaF, Ba, WbF, Bb, Z, Hout, lb * 128, sT + w * 16 * TSTRIDE, w, lane);
    }
}

// ===========================================================================
// r23 mlpB: rows [base, ...), 392 blocks (guards handle the tail).
// ===========================================================================
__global__ __launch_bounds__(256) void k_mlp(const h16* __restrict__ WaF,
                                             const float* __restrict__ Ba,
                                             const h16* __restrict__ WbF,
                                             const float* __restrict__ Bb,
                                             const h16* __restrict__ Zin,
                                             h16* __restrict__ Hout,
                                             int base) {
    __shared__ __align__(16) float sT[4 * 16 * TSTRIDE];
    int t = threadIdx.x;
    int w = t >> 6, lane = t & 63;
    mlp_tile128(WaF, Ba, WbF, Bb, Zin, Hout, base + blockIdx.x * 128,
                sT + w * 16 * TSTRIDE, w, lane);
}

// ===========================================================================
// Fused mean-pool + readout (proven). Unchanged.
// ===========================================================================
__global__ __launch_bounds__(256) void k_poolfinal(const h16* __restrict__ H,
                                                   const int* __restrict__ batch,
                                                   const float* __restrict__ Wl,
                                                   const float* __restrict__ bl,
                                                   float* __restrict__ out) {
    __shared__ float sp[4 * HID];
    int g = blockIdx.x;
    int t = threadIdx.x;
    int lane = t & 63, w = t >> 6;
    int lo = 0, hi = N_NODES;
    while (lo < hi) { int m = (lo + hi) >> 1; if (batch[m] < g) lo = m + 1; else hi = m; }
    int start = lo;
    hi = N_NODES;
    while (lo < hi) { int m = (lo + hi) >> 1; if (batch[m] < g + 1) lo = m + 1; else hi = m; }
    int end = lo;
    float s0 = 0.f, s1 = 0.f, s2 = 0.f, s3 = 0.f;
    int r = start + w;
    for (; r + 12 < end; r += 16) {
        float v0 = (float)H[(size_t)r * HID + lane];
        float v1 = (float)H[(size_t)(r + 4) * HID + lane];
        float v2 = (float)H[(size_t)(r + 8) * HID + lane];
        float v3 = (float)H[(size_t)(r + 12) * HID + lane];
        s0 += v0; s1 += v1; s2 += v2; s3 += v3;
    }
    for (; r < end; r += 4) s0 += (float)H[(size_t)r * HID + lane];
    sp[w * HID + lane] = s0 + s1 + s2 + s3;
    __syncthreads();
    if (t < HID) {
        float tot = sp[t] + sp[HID + t] + sp[2 * HID + t] + sp[3 * HID + t];
        float c = (end > start) ? (float)(end - start) : 1.0f;
        sp[t] = tot / c;
    }
    __syncthreads();
    if (t < OUT_CH) {
        float acc = bl[t];
#pragma unroll
        for (int k = 0; k < HID; ++k) acc += sp[k] * Wl[k * OUT_CH + t];
        out[g * OUT_CH + t] = acc;
    }
}

extern "C" void kernel_launch(void* const* d_in, const int* in_sizes, int n_in,
                              void* d_out, int out_size, void* d_ws, size_t ws_size,
                              hipStream_t stream) {
    const float* x     = (const float*)d_in[0];
    const int*   edge  = (const int*)d_in[1];   // [2][N_EDGES] int32
    const int*   batch = (const int*)d_in[2];   // [N_NODES] int32 (sorted)
    const float* W0  = (const float*)d_in[3];
    const float* b0  = (const float*)d_in[4];
    const float* W1a = (const float*)d_in[5];
    const float* b1a = (const float*)d_in[6];
    const float* W1b = (const float*)d_in[7];
    const float* b1b = (const float*)d_in[8];
    const float* W2a = (const float*)d_in[9];
    const float* b2a = (const float*)d_in[10];
    const float* W2b = (const float*)d_in[11];
    const float* b2b = (const float*)d_in[12];
    const float* W3a = (const float*)d_in[13];
    const float* b3a = (const float*)d_in[14];
    const float* W3b = (const float*)d_in[15];
    const float* b3b = (const float*)d_in[16];
    const float* Wl  = (const float*)d_in[17];
    const float* bl  = (const float*)d_in[18];
    float* out = (float*)d_out;

    const int* src = edge;
    const int* dst = edge + N_EDGES;

    // Workspace: HA | HB | Z (fp16) | cnt | rowptrS | buckets | WF
    h16* HA = (h16*)d_ws;
    h16* HB = HA + (size_t)N_NODES * HID;
    h16* Z  = HB + (size_t)N_NODES * HID;
    int* cnt     = (int*)(Z + (size_t)N_NODES * HID);
    int* rowptrS = cnt + NSUP;
    int* buckets = rowptrS + NSUP * 513;
    h16* WF      = (h16*)(buckets + (size_t)NSUP * SB_CAP);
    h16* W1aF = WF;               // order: W1a, W1b, W2a, W2b, W3a, W3b
    h16* W1bF = WF + 4096 * 1;
    h16* W2aF = WF + 4096 * 2;
    h16* W2bF = WF + 4096 * 3;
    h16* W3aF = WF + 4096 * 4;
    h16* W3bF = WF + 4096 * 5;

    hipMemsetAsync(cnt, 0, NSUP * sizeof(int), stream);
    k_part<<<NPB + NWP, 256, 0, stream>>>(src, dst, cnt, buckets,
        W1a, W1b, W2a, W2b, W3a, W3b, WF);
    k_sortlin<<<NSUP + TILE2, 256, 0, stream>>>(cnt, buckets, rowptrS, W0, b0, x, HA);

    // Layer 1: HA -> HB
    k_aggregate<<<AGA_BLKS, 256, 0, stream>>>(rowptrS, buckets, HA, Z, 0, SPLIT);
    k_aggmlp2<<<AGB_BLKS + MLPA_BLKS, 256, 0, stream>>>(rowptrS, buckets, HA, Z,
        W1aF, b1a, W1bF, b1b, HB);
    k_mlp<<<MLPB_BLKS, 256, 0, stream>>>(W1aF, b1a, W1bF, b1b, Z, HB, SPLIT);

    // Layer 2: HB -> HA
    k_aggregate<<<AGA_BLKS, 256, 0, stream>>>(rowptrS, buckets, HB, Z, 0, SPLIT);
    k_aggmlp2<<<AGB_BLKS + MLPA_BLKS, 256, 0, stream>>>(rowptrS, buckets, HB, Z,
        W2aF, b2a, W2bF, b2b, HA);
    k_mlp<<<MLPB_BLKS, 256, 0, stream>>>(W2aF, b2a, W2bF, b2b, Z, HA, SPLIT);

    // Layer 3: HA -> HB
    k_aggregate<<<AGA_BLKS, 256, 0, stream>>>(rowptrS, buckets, HA, Z, 0, SPLIT);
    k_aggmlp2<<<AGB_BLKS + MLPA_BLKS, 256, 0, stream>>>(rowptrS, buckets, HA, Z,
        W3aF, b3a, W3bF, b3b, HB);
    k_mlp<<<MLPB_BLKS, 256, 0, stream>>>(W3aF, b3a, W3bF, b3b, Z, HB, SPLIT);

    k_poolfinal<<<N_GRAPHS, 256, 0, stream>>>(HB, batch, Wl, bl, out);
}

// Round 10
// 277.085 us; speedup vs baseline: 6.5391x; 1.0210x over previous
//
#include <hip/hip_runtime.h>
#include <hip/hip_fp16.h>

#define N_NODES 100000
#define N_EDGES 1250000
#define HID 64
#define N_GRAPHS 512
#define OUT_CH 16

#define NSUP 196        // super-buckets of 512 nodes
#define SB_CAP 8192     // mean 6378, sigma ~80 -> +22σ
#define E_BLK 2048
#define NPB ((N_EDGES + E_BLK - 1) / E_BLK)  // 611
#define TILE2 ((N_NODES + 127) / 128)  // 782 blocks (2 row-tiles each)
#define NWP 6           // prepped weight matrices (W1a..W3b; W0 handled raw by lin)
#define TSTRIDE 68      // LDS T row stride (floats)
#define AGG_BLOCKS 3125 // 12500 waves x 8 rows = 100000 exactly

typedef _Float16 h16;
typedef _Float16 half2_t __attribute__((ext_vector_type(2)));
typedef _Float16 f16x8 __attribute__((ext_vector_type(8)));
typedef float f32x4 __attribute__((ext_vector_type(4)));

__device__ __forceinline__ void acc8(uint4 u, float* a) {
    half2_t h0 = __builtin_bit_cast(half2_t, u.x);
    half2_t h1 = __builtin_bit_cast(half2_t, u.y);
    half2_t h2 = __builtin_bit_cast(half2_t, u.z);
    half2_t h3 = __builtin_bit_cast(half2_t, u.w);
    a[0] += (float)h0[0]; a[1] += (float)h0[1];
    a[2] += (float)h1[0]; a[3] += (float)h1[1];
    a[4] += (float)h2[0]; a[5] += (float)h2[1];
    a[6] += (float)h3[0]; a[7] += (float)h3[1];
}

__device__ __forceinline__ unsigned pack2(float x, float y) {
    half2_t o;
    o[0] = (h16)x;
    o[1] = (h16)y;
    return __builtin_bit_cast(unsigned, o);
}

// ===========================================================================
// FAT kernel (r18 proven): partition (611 blks) || wprep (6 blks) ||
// input-linear (782 blks) — mutually independent; one dispatch.
// ===========================================================================
__global__ __launch_bounds__(256) void k_fat(const int* __restrict__ src,
                                             const int* __restrict__ dst,
                                             int* __restrict__ cnt,
                                             int* __restrict__ buckets,
                                             const float* __restrict__ W1a,
                                             const float* __restrict__ W1b,
                                             const float* __restrict__ W2a,
                                             const float* __restrict__ W2b,
                                             const float* __restrict__ W3a,
                                             const float* __restrict__ W3b,
                                             h16* __restrict__ WF,
                                             const float* __restrict__ W0,
                                             const float* __restrict__ B0,
                                             const float* __restrict__ Xin,
                                             h16* __restrict__ Hout) {
    __shared__ int hist[256];
    __shared__ int gbase[256];
    __shared__ int tsum[256];
    __shared__ __align__(16) int stage[E_BLK];
    __shared__ __align__(16) float sT[4 * 16 * TSTRIDE];

    int b = blockIdx.x;
    int t = threadIdx.x;

    if (b < NPB) {
        // ---------------- partition (r15 proven) ----------------
        int e0 = b * E_BLK;
        int eN = N_EDGES - e0;
        if (eN > E_BLK) eN = E_BLK;

        hist[t] = 0;
        __syncthreads();
        for (int i = t; i < eN; i += 256) atomicAdd(&hist[dst[e0 + i] >> 9], 1);
        __syncthreads();

        int c = hist[t];
        tsum[t] = c;
        __syncthreads();
        for (int off = 1; off < 256; off <<= 1) {
            int u = (t >= off) ? tsum[t - off] : 0;
            __syncthreads();
            tsum[t] += u;
            __syncthreads();
        }
        int pref = tsum[t] - c;
        if (t < NSUP && c > 0) gbase[t] = atomicAdd(&cnt[t], c);
        hist[t] = pref;
        __syncthreads();

        for (int i = t; i < eN; i += 256) {
            int s = src[e0 + i];
            int d = dst[e0 + i];
            int p = atomicAdd(&hist[d >> 9], 1);
            stage[p] = ((d & 511) << 17) | s;
        }
        __syncthreads();

        if (t < NSUP && c > 0) {
            int lstart = hist[t] - c;
            int gb = gbase[t];
            int cap = SB_CAP - gb;
            int n = c < cap ? c : (cap > 0 ? cap : 0);
            int* dp = buckets + (size_t)t * SB_CAP + gb;
            int r = 0;
            while (r < n && (((size_t)(dp + r)) & 15)) { dp[r] = stage[lstart + r]; ++r; }
            for (; r + 4 <= n; r += 4) {
                int4 v;
                v.x = stage[lstart + r];
                v.y = stage[lstart + r + 1];
                v.z = stage[lstart + r + 2];
                v.w = stage[lstart + r + 3];
                *(int4*)(dp + r) = v;
            }
            for (; r < n; ++r) dp[r] = stage[lstart + r];
        }
    } else if (b < NPB + NWP) {
        // ---------------- weight prep (W1a..W3b only) ----------------
        const float* Ws[NWP] = {W1a, W1b, W2a, W2b, W3a, W3b};
        const float* W = Ws[b - NPB];
        h16* dstW = WF + (size_t)(b - NPB) * 4096;
#pragma unroll
        for (int i = 0; i < 16; ++i) {
            int s = t + 256 * i;
            int k = s >> 6, col = s & 63;
            int kc = k >> 5, quad = (k >> 3) & 3, j = k & 7;
            int c = col >> 4, n = col & 15;
            dstW[((c * 2 + kc) * 4 + quad) * 128 + n * 8 + j] = (h16)W[s];
        }
    } else {
        // ---------------- input linear (r16), raw-W0 fragment load ----------
        int lb = b - NPB - NWP;
        int w = t >> 6, lane = t & 63;
        int n16 = lane & 15, quad = lane >> 4;
        float* T = sT + w * 16 * TSTRIDE;

        f16x8 bw[4][2];
#pragma unroll
        for (int c = 0; c < 4; ++c)
#pragma unroll
            for (int kc = 0; kc < 2; ++kc) {
                f16x8 v;
#pragma unroll
                for (int j = 0; j < 8; ++j)
                    v[j] = (h16)W0[(kc * 32 + quad * 8 + j) * 64 + c * 16 + n16];
                bw[c][kc] = v;
            }
        float bv[4];
#pragma unroll
        for (int c = 0; c < 4; ++c) bv[c] = B0[c * 16 + n16];

#pragma unroll
        for (int tt = 0; tt < 2; ++tt) {
            int rbase = lb * 128 + tt * 64 + w * 16;
            int arow = rbase + n16;
            int crow = arow < N_NODES ? arow : N_NODES - 1;
            f16x8 a[2];
#pragma unroll
            for (int kc = 0; kc < 2; ++kc) {
                const float4* xp = (const float4*)(Xin + (size_t)crow * HID + kc * 32 + quad * 8);
                float4 p = xp[0], q = xp[1];
                f16x8 v;
                v[0] = (h16)p.x; v[1] = (h16)p.y; v[2] = (h16)p.z; v[3] = (h16)p.w;
                v[4] = (h16)q.x; v[5] = (h16)q.y; v[6] = (h16)q.z; v[7] = (h16)q.w;
                a[kc] = v;
            }

            f32x4 acc[4];
#pragma unroll
            for (int c = 0; c < 4; ++c) {
                acc[c] = (f32x4){bv[c], bv[c], bv[c], bv[c]};
#pragma unroll
                for (int kc = 0; kc < 2; ++kc)
                    acc[c] = __builtin_amdgcn_mfma_f32_16x16x32_f16(a[kc], bw[c][kc], acc[c], 0, 0, 0);
            }

#pragma unroll
            for (int c = 0; c < 4; ++c)
#pragma unroll
                for (int r = 0; r < 4; ++r)
                    T[(quad * 4 + r) * TSTRIDE + c * 16 + n16] = fmaxf(acc[c][r], 0.f);
            {
                int rl = lane >> 2, seg = lane & 3;
                int row = rbase + rl;
                if (row < N_NODES) {
                    const float* tr = &T[rl * TSTRIDE + seg * 16];
                    f16x8 o0, o1;
#pragma unroll
                    for (int i = 0; i < 8; ++i) {
                        o0[i] = (h16)tr[i];
                        o1[i] = (h16)tr[8 + i];
                    }
                    f16x8* dp = (f16x8*)(Hout + (size_t)row * HID + seg * 16);
                    dp[0] = o0;
                    dp[1] = o1;
                }
            }
        }
    }
}

// ===========================================================================
// Split (r15 proven): counting sort per super by 9-bit dstLocal. Unchanged.
// ===========================================================================
__global__ __launch_bounds__(256) void k_sort(const int* __restrict__ cnt,
                                              int* __restrict__ buckets,
                                              int* __restrict__ rowptrS) {
    __shared__ int srt[SB_CAP];   // 32 KB
    __shared__ int hist[512];
    __shared__ int curs[512];
    __shared__ int tsum[256];
    int s = blockIdx.x, t = threadIdx.x;
    int n = cnt[s];
    n = n < SB_CAP ? n : SB_CAP;
    int* gb = buckets + (size_t)s * SB_CAP;
    int sBase = s * SB_CAP;

    hist[t] = 0;
    hist[t + 256] = 0;
    __syncthreads();
    for (int i = t; i < n; i += 256) atomicAdd(&hist[gb[i] >> 17], 1);
    __syncthreads();

    int c0 = hist[2 * t], c1 = hist[2 * t + 1];
    int tot = c0 + c1;
    tsum[t] = tot;
    __syncthreads();
    for (int off = 1; off < 256; off <<= 1) {
        int u = (t >= off) ? tsum[t - off] : 0;
        __syncthreads();
        tsum[t] += u;
        __syncthreads();
    }
    int pref = tsum[t] - tot;
    curs[2 * t] = pref;
    curs[2 * t + 1] = pref + c0;
    rowptrS[s * 513 + 2 * t] = sBase + pref;
    rowptrS[s * 513 + 2 * t + 1] = sBase + pref + c0;
    if (t == 255) rowptrS[s * 513 + 512] = sBase + n;
    __syncthreads();

    for (int i = t; i < n; i += 256) {
        int rec = gb[i];
        int pos = atomicAdd(&curs[rec >> 17], 1);
        srt[pos] = rec;
    }
    __syncthreads();
    for (int i = t; i < n; i += 256) gb[i] = srt[i];
}

// ===========================================================================
// Aggregate (r19, measured best): 8 rows/wave, 8 lanes x 16B (dwordx4),
// 8-deep pipelined gathers, 12500 waves. At the random-line service floor.
// ===========================================================================
__global__ __launch_bounds__(256) void k_aggregate(const int* __restrict__ rowptrS,
                                                   const int* __restrict__ buckets,
                                                   const h16* __restrict__ H,
                                                   h16* __restrict__ Z) {
    const uint4* H8 = (const uint4*)H;   // row = 8 x 16B
    uint4* Z8 = (uint4*)Z;
    int lane = threadIdx.x & 63;
    int part = lane >> 3, sub = lane & 7;
    int gwave = (blockIdx.x * 256 + threadIdx.x) >> 6;
    int nw = (gridDim.x * 256) >> 6;
    for (int i0 = gwave * 8; i0 < N_NODES; i0 += nw * 8) {
        int i = i0 + part;
        bool valid = i < N_NODES;
        int iv = valid ? i : N_NODES - 1;
        int s = iv >> 9, l = iv & 511;
        int start = rowptrS[s * 513 + l];
        int end = valid ? rowptrS[s * 513 + l + 1] : start;
        float a[8] = {0.f, 0.f, 0.f, 0.f, 0.f, 0.f, 0.f, 0.f};
        acc8(H8[(size_t)iv * 8 + sub], a);
        int j = start;
        for (; j + 8 <= end; j += 8) {
            int s0 = buckets[j] & 0x1FFFF;
            int s1 = buckets[j + 1] & 0x1FFFF;
            int s2 = buckets[j + 2] & 0x1FFFF;
            int s3 = buckets[j + 3] & 0x1FFFF;
            int s4 = buckets[j + 4] & 0x1FFFF;
            int s5 = buckets[j + 5] & 0x1FFFF;
            int s6 = buckets[j + 6] & 0x1FFFF;
            int s7 = buckets[j + 7] & 0x1FFFF;
            uint4 u0 = H8[(size_t)s0 * 8 + sub];
            uint4 u1 = H8[(size_t)s1 * 8 + sub];
            uint4 u2 = H8[(size_t)s2 * 8 + sub];
            uint4 u3 = H8[(size_t)s3 * 8 + sub];
            uint4 u4 = H8[(size_t)s4 * 8 + sub];
            uint4 u5 = H8[(size_t)s5 * 8 + sub];
            uint4 u6 = H8[(size_t)s6 * 8 + sub];
            uint4 u7 = H8[(size_t)s7 * 8 + sub];
            acc8(u0, a);
            acc8(u1, a);
            acc8(u2, a);
            acc8(u3, a);
            acc8(u4, a);
            acc8(u5, a);
            acc8(u6, a);
            acc8(u7, a);
        }
        if (j + 4 <= end) {
            int s0 = buckets[j] & 0x1FFFF;
            int s1 = buckets[j + 1] & 0x1FFFF;
            int s2 = buckets[j + 2] & 0x1FFFF;
            int s3 = buckets[j + 3] & 0x1FFFF;
            uint4 u0 = H8[(size_t)s0 * 8 + sub];
            uint4 u1 = H8[(size_t)s1 * 8 + sub];
            uint4 u2 = H8[(size_t)s2 * 8 + sub];
            uint4 u3 = H8[(size_t)s3 * 8 + sub];
            acc8(u0, a);
            acc8(u1, a);
            acc8(u2, a);
            acc8(u3, a);
            j += 4;
        }
        if (j + 2 <= end) {
            int s0 = buckets[j] & 0x1FFFF;
            int s1 = buckets[j + 1] & 0x1FFFF;
            uint4 u0 = H8[(size_t)s0 * 8 + sub];
            uint4 u1 = H8[(size_t)s1 * 8 + sub];
            acc8(u0, a);
            acc8(u1, a);
            j += 2;
        }
        if (j < end) {
            int s0 = buckets[j] & 0x1FFFF;
            acc8(H8[(size_t)s0 * 8 + sub], a);
        }
        if (valid) {
            uint4 o;
            o.x = pack2(a[0], a[1]);
            o.y = pack2(a[2], a[3]);
            o.z = pack2(a[4], a[5]);
            o.w = pack2(a[6], a[7]);
            Z8[(size_t)i * 8 + sub] = o;
        }
    }
}

// ===========================================================================
// MFMA MLP (r16 proven): 2 row-tiles (128 rows) per block, B-frags reused.
// ===========================================================================
__global__ __launch_bounds__(256) void k_mlp(const h16* __restrict__ WaF,
                                             const float* __restrict__ Ba,
                                             const h16* __restrict__ WbF,
                                             const float* __restrict__ Bb,
                                             const h16* __restrict__ Zin,
                                             h16* __restrict__ Hout) {
    __shared__ __align__(16) float sT[4 * 16 * TSTRIDE];
    int t = threadIdx.x;
    int w = t >> 6, lane = t & 63;
    int n16 = lane & 15, quad = lane >> 4;
    float* T = sT + w * 16 * TSTRIDE;

    f16x8 bwa[4][2], bwb[4][2];
#pragma unroll
    for (int c = 0; c < 4; ++c)
#pragma unroll
        for (int kc = 0; kc < 2; ++kc) {
            int f = ((c * 2 + kc) * 4 + quad) * 128 + n16 * 8;
            bwa[c][kc] = *(const f16x8*)(WaF + f);
            bwb[c][kc] = *(const f16x8*)(WbF + f);
        }
    float bva[4], bvb[4];
#pragma unroll
    for (int c = 0; c < 4; ++c) {
        bva[c] = Ba[c * 16 + n16];
        bvb[c] = Bb[c * 16 + n16];
    }

#pragma unroll
    for (int tt = 0; tt < 2; ++tt) {
        int rbase = blockIdx.x * 128 + tt * 64 + w * 16;
        int arow = rbase + n16;
        int crow = arow < N_NODES ? arow : N_NODES - 1;
        const f16x8* zp = (const f16x8*)(Zin + (size_t)crow * HID + quad * 8);
        f16x8 a0 = zp[0];
        f16x8 a1 = zp[4];

        f32x4 acc[4];
#pragma unroll
        for (int c = 0; c < 4; ++c) {
            acc[c] = (f32x4){bva[c], bva[c], bva[c], bva[c]};
            acc[c] = __builtin_amdgcn_mfma_f32_16x16x32_f16(a0, bwa[c][0], acc[c], 0, 0, 0);
            acc[c] = __builtin_amdgcn_mfma_f32_16x16x32_f16(a1, bwa[c][1], acc[c], 0, 0, 0);
        }

#pragma unroll
        for (int c = 0; c < 4; ++c)
#pragma unroll
            for (int r = 0; r < 4; ++r)
                T[(quad * 4 + r) * TSTRIDE + c * 16 + n16] = fmaxf(acc[c][r], 0.f);

        f16x8 ta[2];
#pragma unroll
        for (int kc = 0; kc < 2; ++kc) {
            float4 p = *(const float4*)&T[n16 * TSTRIDE + kc * 32 + quad * 8];
            float4 q = *(const float4*)&T[n16 * TSTRIDE + kc * 32 + quad * 8 + 4];
            f16x8 v;
            v[0] = (h16)p.x; v[1] = (h16)p.y; v[2] = (h16)p.z; v[3] = (h16)p.w;
            v[4] = (h16)q.x; v[5] = (h16)q.y; v[6] = (h16)q.z; v[7] = (h16)q.w;
            ta[kc] = v;
        }

#pragma unroll
        for (int c = 0; c < 4; ++c) {
            acc[c] = (f32x4){bvb[c], bvb[c], bvb[c], bvb[c]};
            acc[c] = __builtin_amdgcn_mfma_f32_16x16x32_f16(ta[0], bwb[c][0], acc[c], 0, 0, 0);
            acc[c] = __builtin_amdgcn_mfma_f32_16x16x32_f16(ta[1], bwb[c][1], acc[c], 0, 0, 0);
        }

#pragma unroll
        for (int c = 0; c < 4; ++c)
#pragma unroll
            for (int r = 0; r < 4; ++r)
                T[(quad * 4 + r) * TSTRIDE + c * 16 + n16] = fmaxf(acc[c][r], 0.f);
        {
            int rl = lane >> 2, seg = lane & 3;
            int row = rbase + rl;
            if (row < N_NODES) {
                const float* tr = &T[rl * TSTRIDE + seg * 16];
                f16x8 o0, o1;
#pragma unroll
                for (int i = 0; i < 8; ++i) {
                    o0[i] = (h16)tr[i];
                    o1[i] = (h16)tr[8 + i];
                }
                f16x8* dp = (f16x8*)(Hout + (size_t)row * HID + seg * 16);
                dp[0] = o0;
                dp[1] = o1;
            }
        }
    }
}

// ===========================================================================
// Fused mean-pool + readout (r16 proven). Unchanged.
// ===========================================================================
__global__ __launch_bounds__(256) void k_poolfinal(const h16* __restrict__ H,
                                                   const int* __restrict__ batch,
                                                   const float* __restrict__ Wl,
                                                   const float* __restrict__ bl,
                                                   float* __restrict__ out) {
    __shared__ float sp[4 * HID];
    int g = blockIdx.x;
    int t = threadIdx.x;
    int lane = t & 63, w = t >> 6;
    int lo = 0, hi = N_NODES;
    while (lo < hi) { int m = (lo + hi) >> 1; if (batch[m] < g) lo = m + 1; else hi = m; }
    int start = lo;
    hi = N_NODES;
    while (lo < hi) { int m = (lo + hi) >> 1; if (batch[m] < g + 1) lo = m + 1; else hi = m; }
    int end = lo;
    float s0 = 0.f, s1 = 0.f, s2 = 0.f, s3 = 0.f;
    int r = start + w;
    for (; r + 12 < end; r += 16) {
        float v0 = (float)H[(size_t)r * HID + lane];
        float v1 = (float)H[(size_t)(r + 4) * HID + lane];
        float v2 = (float)H[(size_t)(r + 8) * HID + lane];
        float v3 = (float)H[(size_t)(r + 12) * HID + lane];
        s0 += v0; s1 += v1; s2 += v2; s3 += v3;
    }
    for (; r < end; r += 4) s0 += (float)H[(size_t)r * HID + lane];
    sp[w * HID + lane] = s0 + s1 + s2 + s3;
    __syncthreads();
    if (t < HID) {
        float tot = sp[t] + sp[HID + t] + sp[2 * HID + t] + sp[3 * HID + t];
        float c = (end > start) ? (float)(end - start) : 1.0f;
        sp[t] = tot / c;
    }
    __syncthreads();
    if (t < OUT_CH) {
        float acc = bl[t];
#pragma unroll
        for (int k = 0; k < HID; ++k) acc += sp[k] * Wl[k * OUT_CH + t];
        out[g * OUT_CH + t] = acc;
    }
}

extern "C" void kernel_launch(void* const* d_in, const int* in_sizes, int n_in,
                              void* d_out, int out_size, void* d_ws, size_t ws_size,
                              hipStream_t stream) {
    const float* x     = (const float*)d_in[0];
    const int*   edge  = (const int*)d_in[1];   // [2][N_EDGES] int32
    const int*   batch = (const int*)d_in[2];   // [N_NODES] int32 (sorted)
    const float* W0  = (const float*)d_in[3];
    const float* b0  = (const float*)d_in[4];
    const float* W1a = (const float*)d_in[5];
    const float* b1a = (const float*)d_in[6];
    const float* W1b = (const float*)d_in[7];
    const float* b1b = (const float*)d_in[8];
    const float* W2a = (const float*)d_in[9];
    const float* b2a = (const float*)d_in[10];
    const float* W2b = (const float*)d_in[11];
    const float* b2b = (const float*)d_in[12];
    const float* W3a = (const float*)d_in[13];
    const float* b3a = (const float*)d_in[14];
    const float* W3b = (const float*)d_in[15];
    const float* b3b = (const float*)d_in[16];
    const float* Wl  = (const float*)d_in[17];
    const float* bl  = (const float*)d_in[18];
    float* out = (float*)d_out;

    const int* src = edge;
    const int* dst = edge + N_EDGES;

    // Workspace: HA(fp16) | Z(fp16) | cnt | rowptrS | buckets | WF(fp16 x6)
    h16* HA = (h16*)d_ws;
    h16* Z  = HA + (size_t)N_NODES * HID;
    int* cnt     = (int*)(Z + (size_t)N_NODES * HID);
    int* rowptrS = cnt + NSUP;
    int* buckets = rowptrS + NSUP * 513;
    h16* WF      = (h16*)(buckets + (size_t)NSUP * SB_CAP);
    h16* W1aF = WF;               // order: W1a, W1b, W2a, W2b, W3a, W3b
    h16* W1bF = WF + 4096 * 1;
    h16* W2aF = WF + 4096 * 2;
    h16* W2bF = WF + 4096 * 3;
    h16* W3aF = WF + 4096 * 4;
    h16* W3bF = WF + 4096 * 5;

    hipMemsetAsync(cnt, 0, NSUP * sizeof(int), stream);
    // partition || wprep || input-linear in one dispatch
    k_fat<<<NPB + NWP + TILE2, 256, 0, stream>>>(src, dst, cnt, buckets,
        W1a, W1b, W2a, W2b, W3a, W3b, WF, W0, b0, x, HA);
    k_sort<<<NSUP, 256, 0, stream>>>(cnt, buckets, rowptrS);

    k_aggregate<<<AGG_BLOCKS, 256, 0, stream>>>(rowptrS, buckets, HA, Z);
    k_mlp<<<TILE2, 256, 0, stream>>>(W1aF, b1a, W1bF, b1b, Z, HA);

    k_aggregate<<<AGG_BLOCKS, 256, 0, stream>>>(rowptrS, buckets, HA, Z);
    k_mlp<<<TILE2, 256, 0, stream>>>(W2aF, b2a, W2bF, b2b, Z, HA);

    k_aggregate<<<AGG_BLOCKS, 256, 0, stream>>>(rowptrS, buckets, HA, Z);
    k_mlp<<<TILE2, 256, 0, stream>>>(W3aF, b3a, W3bF, b3b, Z, HA);

    k_poolfinal<<<N_GRAPHS, 256, 0, stream>>>(HA, batch, Wl, bl, out);
}